// Round 18
// baseline (153.009 us; speedup 1.0000x reference)
//
#include <hip/hip_runtime.h>
#include <hip/hip_bf16.h>
#include <stdint.h>

#define N_ROWS 8192
#define DIM    1024            // elements per row; i8 => also bytes per row
#define TEMP_INV 10.0f
#define NCHUNK 64
#define BM 128
#define BN 128
#define BKB 128                // K-bytes per tile (i8: 128 elems)
#define BUFB 16384             // bytes per LDS buffer (128 rows x 128 B)
#define NEGINF (-__builtin_inff())

typedef __attribute__((ext_vector_type(4))) int i32x4;

__device__ __forceinline__ void gload_lds16(const void* g, void* l) {
  __builtin_amdgcn_global_load_lds(
      (const __attribute__((address_space(1))) unsigned int*)g,
      (__attribute__((address_space(3))) unsigned int*)l, 16, 0, 0);
}

// -------- Kernel 1: L2-normalize rows -> per-row-scaled int8 (1 wave = 1 row) --------
__global__ void norm_i8_kernel(const float* __restrict__ ctx,
                               const float* __restrict__ gls,
                               unsigned char* __restrict__ Cn,
                               unsigned char* __restrict__ Gn,
                               float* __restrict__ CnS,
                               float* __restrict__ GnS) {
  const int wid = blockIdx.x * 4 + (threadIdx.x >> 6);   // row 0..16383
  const int lane = threadIdx.x & 63;
  const float* src;
  unsigned char* dst;
  float* sdst;
  int srow;
  if (wid < N_ROWS) { src = ctx + (size_t)wid * DIM; dst = Cn + (size_t)wid * DIM; sdst = CnS; srow = wid; }
  else { srow = wid - N_ROWS; src = gls + (size_t)srow * DIM; dst = Gn + (size_t)srow * DIM; sdst = GnS; }
  float4 v[4];
  float ss = 0.f, mx = 0.f;
  #pragma unroll
  for (int q = 0; q < 4; ++q) {
    v[q] = ((const float4*)src)[lane + q * 64];
    ss += v[q].x * v[q].x + v[q].y * v[q].y + v[q].z * v[q].z + v[q].w * v[q].w;
    mx = fmaxf(mx, fmaxf(fmaxf(fabsf(v[q].x), fabsf(v[q].y)),
                         fmaxf(fabsf(v[q].z), fabsf(v[q].w))));
  }
  #pragma unroll
  for (int m = 1; m < 64; m <<= 1) {
    ss += __shfl_xor(ss, m);
    mx = fmaxf(mx, __shfl_xor(mx, m));
  }
  const float inv = 1.0f / fmaxf(sqrtf(ss), 1e-12f);
  const float amax = fmaxf(mx, 1e-20f);
  const float r127 = 127.0f / amax;
  #pragma unroll
  for (int q = 0; q < 4; ++q) {
    int c0 = __float2int_rn(v[q].x * r127);
    int c1 = __float2int_rn(v[q].y * r127);
    int c2 = __float2int_rn(v[q].z * r127);
    int c3 = __float2int_rn(v[q].w * r127);
    unsigned int pk = (c0 & 255) | ((c1 & 255) << 8) | ((c2 & 255) << 16) | ((unsigned int)(c3 & 255) << 24);
    *(unsigned int*)(dst + (size_t)(lane + q * 64) * 4) = pk;
  }
  if (lane == 0) sdst[srow] = amax * inv * (1.0f / 127.0f);
}

// staging: 8 gload_lds into buffer B for K-tile KT (verbatim r16 addressing + buf base)
#define STAGE(B, KT) do { \
    const int k0_ = (KT) * BKB; \
    _Pragma("unroll") \
    for (int i_ = 0; i_ < 4; ++i_) { \
      int r_ = wv * 4 + i_; \
      gload_lds16(Cn + (size_t)(row0 + r_*8 + srow) * DIM + k0_ + scol*16, &As[(B)*BUFB + r_ * 1024]); \
    } \
    _Pragma("unroll") \
    for (int i_ = 0; i_ < 4; ++i_) { \
      int r_ = wv * 4 + i_; \
      gload_lds16(Gn + (size_t)(col0 + r_*8 + srow) * DIM + k0_ + scol*16, &Bs[(B)*BUFB + r_ * 1024]); \
    } \
  } while (0)

// compute one K-tile from buffer B: 2 half-phases x 16 i8 MFMAs (verbatim r16)
#define COMPUTE(B) do { \
    { \
      i32x4 af[4], bfr[4]; \
      _Pragma("unroll") \
      for (int m_ = 0; m_ < 4; ++m_) \
        af[m_] = *(const i32x4*)&As[(B)*BUFB + (wr*64 + m_*16 + fr) * BKB + sl0]; \
      _Pragma("unroll") \
      for (int n_ = 0; n_ < 4; ++n_) \
        bfr[n_] = *(const i32x4*)&Bs[(B)*BUFB + (wc*64 + n_*16 + fr) * BKB + sl0]; \
      __builtin_amdgcn_s_setprio(1); \
      _Pragma("unroll") \
      for (int m_ = 0; m_ < 4; ++m_) \
        _Pragma("unroll") \
        for (int n_ = 0; n_ < 4; ++n_) \
          acc[m_][n_] = __builtin_amdgcn_mfma_i32_16x16x64_i8(af[m_], bfr[n_], acc[m_][n_], 0, 0, 0); \
      __builtin_amdgcn_s_setprio(0); \
    } \
    { \
      i32x4 af[4], bfr[4]; \
      _Pragma("unroll") \
      for (int m_ = 0; m_ < 4; ++m_) \
        af[m_] = *(const i32x4*)&As[(B)*BUFB + (wr*64 + m_*16 + fr) * BKB + sl1]; \
      _Pragma("unroll") \
      for (int n_ = 0; n_ < 4; ++n_) \
        bfr[n_] = *(const i32x4*)&Bs[(B)*BUFB + (wc*64 + n_*16 + fr) * BKB + sl1]; \
      __builtin_amdgcn_s_setprio(1); \
      _Pragma("unroll") \
      for (int m_ = 0; m_ < 4; ++m_) \
        _Pragma("unroll") \
        for (int n_ = 0; n_ < 4; ++n_) \
          acc[m_][n_] = __builtin_amdgcn_mfma_i32_16x16x64_i8(af[m_], bfr[n_], acc[m_][n_], 0, 0, 0); \
      __builtin_amdgcn_s_setprio(0); \
    } \
  } while (0)

// -------- Kernel 2: fused i8 GEMM, double-buffered LDS (T3 minimum 2-phase) --------
// Stage tile t+1 BEFORE computing tile t; one vmcnt(0)+barrier per K-tile.
// WAR-safe: reads of a buffer are consumed by MFMAs before the barrier that
// precedes its re-staging. RAW-safe: vmcnt(0)+barrier before a buffer is read.
__global__ __launch_bounds__(256, 2)
void gemm_reduce_kernel(const unsigned char* __restrict__ Cn,
                        const unsigned char* __restrict__ Gn,
                        const float* __restrict__ CnS,
                        const float* __restrict__ GnS,
                        const int* __restrict__ labels,
                        float* __restrict__ ws_sp,
                        float* __restrict__ ws_sa,
                        float* __restrict__ ws_mx) {
  __shared__ __align__(16) unsigned char As[2 * BUFB];   // 32 KiB
  __shared__ __align__(16) unsigned char Bs[2 * BUFB];   // 32 KiB
  __shared__ float red_sa[2][BM];
  __shared__ float red_sp[2][BM];
  __shared__ float red_mx[2][BM];

  const int tid = threadIdx.x;
  const int lane = tid & 63;
  const int wv = tid >> 6;
  const int wr = wv >> 1, wc = wv & 1;
  const int row0 = blockIdx.x * BM;
  const int chunk = blockIdx.y;
  const int col0 = chunk * BN;
  const int g = lane >> 4;        // k-group 0..3
  const int fr = lane & 15;       // fragment row/col 0..15
  const int fr7 = fr & 7;

  // staging constants (verbatim r2/9/13/16; swizzle pre-applied on global src)
  const int srow = lane >> 3;                 // 0..7
  const int scol = (lane & 7) ^ srow;         // pre-swizzled 16B slot (8/row)

  // frag read slot byte-offsets (row&7 == fr&7): slots g and 4+g
  const int sl0 = ((g) ^ fr7) << 4;
  const int sl1 = ((4 + g) ^ fr7) << 4;

  i32x4 acc[4][4];
  #pragma unroll
  for (int m = 0; m < 4; ++m)
    #pragma unroll
    for (int n = 0; n < 4; ++n) {
      i32x4 z = {0, 0, 0, 0};
      acc[m][n] = z;
    }

  // prologue: tile 0 into buf0
  STAGE(0, 0);
  asm volatile("s_waitcnt vmcnt(0)" ::: "memory");
  __syncthreads();

  // 8 K-tiles: buf0 holds even tiles, buf1 odd tiles
  #pragma unroll
  for (int kk = 0; kk < 4; ++kk) {
    STAGE(1, 2 * kk + 1);            // issue next tile while computing current
    COMPUTE(0);                      // tile 2kk
    asm volatile("s_waitcnt vmcnt(0)" ::: "memory");
    __syncthreads();
    if (kk < 3) STAGE(0, 2 * kk + 2);
    COMPUTE(1);                      // tile 2kk+1
    asm volatile("s_waitcnt vmcnt(0)" ::: "memory");
    __syncthreads();
  }

  // epilogue (once per block): dequant + exp + masked reduction (verbatim r16)
  int cl[4], cg[4];
  float invB[4];
  #pragma unroll
  for (int n = 0; n < 4; ++n) {
    cg[n] = col0 + wc*64 + n*16 + fr;
    cl[n] = labels[cg[n]];
    invB[n] = GnS[cg[n]];
  }
  #pragma unroll
  for (int m = 0; m < 4; ++m) {
    #pragma unroll
    for (int j = 0; j < 4; ++j) {
      const int rloc = wr*64 + m*16 + g*4 + j;
      const int rgi = row0 + rloc;
      const int rlab = labels[rgi];
      const float fA = CnS[rgi] * TEMP_INV;
      float va = 0.f, vp = 0.f, vm = NEGINF;
      #pragma unroll
      for (int n = 0; n < 4; ++n) {
        float s10 = (float)acc[m][n][j] * fA * invB[n];
        float e = __expf(s10);
        bool offd = (rgi != cg[n]);
        float ea = offd ? e : 0.f;
        va += ea;
        vp += (rlab == cl[n]) ? ea : 0.f;
        vm = offd ? fmaxf(vm, s10) : vm;
      }
      #pragma unroll
      for (int mk = 1; mk < 16; mk <<= 1) {
        va += __shfl_xor(va, mk);
        vp += __shfl_xor(vp, mk);
        vm = fmaxf(vm, __shfl_xor(vm, mk));
      }
      if (fr == 0) {
        red_sa[wc][rloc] = va;
        red_sp[wc][rloc] = vp;
        red_mx[wc][rloc] = vm;
      }
    }
  }
  __syncthreads();
  if (tid < BM) {
    size_t o = (size_t)chunk * N_ROWS + row0 + tid;
    ws_sa[o] = red_sa[0][tid] + red_sa[1][tid];
    ws_sp[o] = red_sp[0][tid] + red_sp[1][tid];
    ws_mx[o] = fmaxf(red_mx[0][tid], red_mx[1][tid]);
  }
}

// -------- Kernel 3: combine chunk partials -> per-row loss -> 32 block partials --------
__global__ void finalize_rows_kernel(const float* __restrict__ ws_sp,
                                     const float* __restrict__ ws_sa,
                                     const float* __restrict__ ws_mx,
                                     float* __restrict__ ws_part) {
  int r = blockIdx.x * blockDim.x + threadIdx.x;
  float sp = 0.f, sa = 0.f, mx = NEGINF;
  #pragma unroll 8
  for (int c = 0; c < NCHUNK; ++c) {
    sp += ws_sp[(size_t)c * N_ROWS + r];
    sa += ws_sa[(size_t)c * N_ROWS + r];
    mx = fmaxf(mx, ws_mx[(size_t)c * N_ROWS + r]);
  }
  float frac = (sp + 1e-8f) / (sa + 1e-8f);
  frac = fminf(fmaxf(frac, 1e-8f), 1.0f);
  float loss = -logf(frac);
  if (sp == 0.0f) loss = -mx;   // no-positives fallback (every exp term > 0)
  int t = threadIdx.x;
  #pragma unroll
  for (int m = 1; m < 64; m <<= 1) loss += __shfl_xor(loss, m);
  __shared__ float wsum[4];
  if ((t & 63) == 0) wsum[t >> 6] = loss;
  __syncthreads();
  if (t == 0) ws_part[blockIdx.x] = (wsum[0] + wsum[1]) + (wsum[2] + wsum[3]);
}

// -------- Kernel 4: deterministic mean over 32 block partials --------
__global__ void mean_kernel(const float* __restrict__ ws_part, float* __restrict__ out) {
  int t = threadIdx.x;                       // 64 threads
  float s = (t < N_ROWS / 256) ? ws_part[t] : 0.f;
  #pragma unroll
  for (int m = 1; m < 64; m <<= 1) s += __shfl_xor(s, m);
  if (t == 0) out[0] = s * (1.0f / N_ROWS);
}

extern "C" void kernel_launch(void* const* d_in, const int* in_sizes, int n_in,
                              void* d_out, int out_size, void* d_ws, size_t ws_size,
                              hipStream_t stream) {
  const float* ctx = (const float*)d_in[0];
  const float* gls = (const float*)d_in[1];
  const int* labels = (const int*)d_in[2];
  float* out = (float*)d_out;

  char* ws = (char*)d_ws;
  unsigned char* Cn = (unsigned char*)ws;                                 // 8 MiB
  unsigned char* Gn = (unsigned char*)(ws + (size_t)N_ROWS * DIM);        // 8 MiB
  float* CnS = (float*)(ws + (size_t)2 * N_ROWS * DIM);                   // 32 KiB
  float* GnS = CnS + N_ROWS;                                              // 32 KiB
  float* ws_sp = GnS + N_ROWS;
  float* ws_sa = ws_sp + (size_t)NCHUNK * N_ROWS;
  float* ws_mx = ws_sa + (size_t)NCHUNK * N_ROWS;
  float* ws_part = ws_mx + (size_t)NCHUNK * N_ROWS;

  hipLaunchKernelGGL(norm_i8_kernel, dim3(4096), dim3(256), 0, stream,
                     ctx, gls, Cn, Gn, CnS, GnS);
  hipLaunchKernelGGL(gemm_reduce_kernel, dim3(N_ROWS / BM, NCHUNK), dim3(256), 0, stream,
                     Cn, Gn, CnS, GnS, labels, ws_sp, ws_sa, ws_mx);
  hipLaunchKernelGGL(finalize_rows_kernel, dim3(N_ROWS / 256), dim3(256), 0, stream,
                     ws_sp, ws_sa, ws_mx, ws_part);
  hipLaunchKernelGGL(mean_kernel, dim3(1), dim3(64), 0, stream, ws_part, out);
}

// Round 19
// 141.870 us; speedup vs baseline: 1.0785x; 1.0785x over previous
//
#include <hip/hip_runtime.h>
#include <hip/hip_bf16.h>
#include <stdint.h>

#define N_ROWS 8192
#define DIM    1024            // elements per row; i8 => also bytes per row
#define TEMP_INV 10.0f
#define NCHUNK 64
#define BM 128
#define BN 128
#define BKB 128                // K-bytes per tile (i8: 128 elems)
#define NEGINF (-__builtin_inff())

typedef __attribute__((ext_vector_type(4))) int i32x4;

__device__ __forceinline__ void gload_lds16(const void* g, void* l) {
  __builtin_amdgcn_global_load_lds(
      (const __attribute__((address_space(1))) unsigned int*)g,
      (__attribute__((address_space(3))) unsigned int*)l, 16, 0, 0);
}

// -------- Kernel 1: L2-normalize rows -> per-row-scaled int8 (1 wave = 1 row) --------
// q_i = rint(127 * x_i / max|x|)  (norm cancels); scale = max|x| * inv_norm / 127
// so sim = idot * scaleA * scaleB.
__global__ void norm_i8_kernel(const float* __restrict__ ctx,
                               const float* __restrict__ gls,
                               unsigned char* __restrict__ Cn,
                               unsigned char* __restrict__ Gn,
                               float* __restrict__ CnS,
                               float* __restrict__ GnS) {
  const int wid = blockIdx.x * 4 + (threadIdx.x >> 6);   // row 0..16383
  const int lane = threadIdx.x & 63;
  const float* src;
  unsigned char* dst;
  float* sdst;
  int srow;
  if (wid < N_ROWS) { src = ctx + (size_t)wid * DIM; dst = Cn + (size_t)wid * DIM; sdst = CnS; srow = wid; }
  else { srow = wid - N_ROWS; src = gls + (size_t)srow * DIM; dst = Gn + (size_t)srow * DIM; sdst = GnS; }
  float4 v[4];
  float ss = 0.f, mx = 0.f;
  #pragma unroll
  for (int q = 0; q < 4; ++q) {
    v[q] = ((const float4*)src)[lane + q * 64];
    ss += v[q].x * v[q].x + v[q].y * v[q].y + v[q].z * v[q].z + v[q].w * v[q].w;
    mx = fmaxf(mx, fmaxf(fmaxf(fabsf(v[q].x), fabsf(v[q].y)),
                         fmaxf(fabsf(v[q].z), fabsf(v[q].w))));
  }
  #pragma unroll
  for (int m = 1; m < 64; m <<= 1) {
    ss += __shfl_xor(ss, m);
    mx = fmaxf(mx, __shfl_xor(mx, m));
  }
  const float inv = 1.0f / fmaxf(sqrtf(ss), 1e-12f);
  const float amax = fmaxf(mx, 1e-20f);
  const float r127 = 127.0f / amax;
  #pragma unroll
  for (int q = 0; q < 4; ++q) {
    int c0 = __float2int_rn(v[q].x * r127);
    int c1 = __float2int_rn(v[q].y * r127);
    int c2 = __float2int_rn(v[q].z * r127);
    int c3 = __float2int_rn(v[q].w * r127);
    unsigned int pk = (c0 & 255) | ((c1 & 255) << 8) | ((c2 & 255) << 16) | ((unsigned int)(c3 & 255) << 24);
    *(unsigned int*)(dst + (size_t)(lane + q * 64) * 4) = pk;
  }
  if (lane == 0) sdst[srow] = amax * inv * (1.0f / 127.0f);
}

// -------- Kernel 2: fused i8 GEMM (mfma_i32_16x16x64_i8, BK=128B) + exp + masked reductions --------
// Best-measured structure (r16): single-buffer 2-barrier loop, 4 blocks/CU,
// VGPR 68, zero spill, zero bank conflicts, gemm ~118.8 us.
__global__ __launch_bounds__(256, 2)
void gemm_reduce_kernel(const unsigned char* __restrict__ Cn,
                        const unsigned char* __restrict__ Gn,
                        const float* __restrict__ CnS,
                        const float* __restrict__ GnS,
                        const int* __restrict__ labels,
                        float* __restrict__ ws_sp,
                        float* __restrict__ ws_sa,
                        float* __restrict__ ws_mx) {
  __shared__ __align__(16) unsigned char As[BM * BKB];   // 16 KiB
  __shared__ __align__(16) unsigned char Bs[BN * BKB];   // 16 KiB
  __shared__ float red_sa[2][BM];
  __shared__ float red_sp[2][BM];
  __shared__ float red_mx[2][BM];

  const int tid = threadIdx.x;
  const int lane = tid & 63;
  const int wv = tid >> 6;
  const int wr = wv >> 1, wc = wv & 1;
  const int row0 = blockIdx.x * BM;
  const int chunk = blockIdx.y;
  const int col0 = chunk * BN;
  const int g = lane >> 4;        // k-group 0..3
  const int fr = lane & 15;       // fragment row/col 0..15
  const int fr7 = fr & 7;

  // staging: region r = wv*4+i covers rows r*8..r*8+7 (128 B each).
  // LDS written linearly (base + lane*16B); XOR swizzle pre-applied on the
  // GLOBAL source 16B-slot (slot ^= row&7)  [rule #21; verified r2/9/13/15/16].
  const int srow = lane >> 3;                 // 0..7
  const int scol = (lane & 7) ^ srow;         // pre-swizzled 16B slot (8/row)

  // frag read slot byte-offsets (row&7 == fr&7): slots g and 4+g
  const int sl0 = ((g) ^ fr7) << 4;
  const int sl1 = ((4 + g) ^ fr7) << 4;

  i32x4 acc[4][4];
  #pragma unroll
  for (int m = 0; m < 4; ++m)
    #pragma unroll
    for (int n = 0; n < 4; ++n) {
      i32x4 z = {0, 0, 0, 0};
      acc[m][n] = z;
    }

  for (int kt = 0; kt < DIM / BKB; ++kt) {   // 8 iterations
    const int k0 = kt * BKB;
    #pragma unroll
    for (int i = 0; i < 4; ++i) {
      int r = wv * 4 + i;
      gload_lds16(Cn + (size_t)(row0 + r*8 + srow) * DIM + k0 + scol*16, &As[r * 1024]);
    }
    #pragma unroll
    for (int i = 0; i < 4; ++i) {
      int r = wv * 4 + i;
      gload_lds16(Gn + (size_t)(col0 + r*8 + srow) * DIM + k0 + scol*16, &Bs[r * 1024]);
    }
    __syncthreads();
    // half-phase 0: slot g (16B/lane), 16 MFMAs (K=64)
    {
      i32x4 af[4], bfr[4];
      #pragma unroll
      for (int m = 0; m < 4; ++m)
        af[m] = *(const i32x4*)&As[(wr*64 + m*16 + fr) * BKB + sl0];
      #pragma unroll
      for (int n = 0; n < 4; ++n)
        bfr[n] = *(const i32x4*)&Bs[(wc*64 + n*16 + fr) * BKB + sl0];
      __builtin_amdgcn_s_setprio(1);
      #pragma unroll
      for (int m = 0; m < 4; ++m)
        #pragma unroll
        for (int n = 0; n < 4; ++n)
          acc[m][n] = __builtin_amdgcn_mfma_i32_16x16x64_i8(af[m], bfr[n], acc[m][n], 0, 0, 0);
      __builtin_amdgcn_s_setprio(0);
    }
    // half-phase 1: slot 4+g, 16 MFMAs
    {
      i32x4 af[4], bfr[4];
      #pragma unroll
      for (int m = 0; m < 4; ++m)
        af[m] = *(const i32x4*)&As[(wr*64 + m*16 + fr) * BKB + sl1];
      #pragma unroll
      for (int n = 0; n < 4; ++n)
        bfr[n] = *(const i32x4*)&Bs[(wc*64 + n*16 + fr) * BKB + sl1];
      __builtin_amdgcn_s_setprio(1);
      #pragma unroll
      for (int m = 0; m < 4; ++m)
        #pragma unroll
        for (int n = 0; n < 4; ++n)
          acc[m][n] = __builtin_amdgcn_mfma_i32_16x16x64_i8(af[m], bfr[n], acc[m][n], 0, 0, 0);
      __builtin_amdgcn_s_setprio(0);
    }
    __syncthreads();
  }

  // epilogue (once per block): dequant + exp + masked reduction
  int cl[4], cg[4];
  float invB[4];
  #pragma unroll
  for (int n = 0; n < 4; ++n) {
    cg[n] = col0 + wc*64 + n*16 + fr;
    cl[n] = labels[cg[n]];
    invB[n] = GnS[cg[n]];
  }
  #pragma unroll
  for (int m = 0; m < 4; ++m) {
    #pragma unroll
    for (int j = 0; j < 4; ++j) {
      const int rloc = wr*64 + m*16 + g*4 + j;
      const int rgi = row0 + rloc;
      const int rlab = labels[rgi];
      const float fA = CnS[rgi] * TEMP_INV;
      float va = 0.f, vp = 0.f, vm = NEGINF;
      #pragma unroll
      for (int n = 0; n < 4; ++n) {
        float s10 = (float)acc[m][n][j] * fA * invB[n];
        float e = __expf(s10);
        bool offd = (rgi != cg[n]);
        float ea = offd ? e : 0.f;
        va += ea;
        vp += (rlab == cl[n]) ? ea : 0.f;
        vm = offd ? fmaxf(vm, s10) : vm;
      }
      #pragma unroll
      for (int mk = 1; mk < 16; mk <<= 1) {
        va += __shfl_xor(va, mk);
        vp += __shfl_xor(vp, mk);
        vm = fmaxf(vm, __shfl_xor(vm, mk));
      }
      if (fr == 0) {
        red_sa[wc][rloc] = va;
        red_sp[wc][rloc] = vp;
        red_mx[wc][rloc] = vm;
      }
    }
  }
  __syncthreads();
  if (tid < BM) {
    size_t o = (size_t)chunk * N_ROWS + row0 + tid;
    ws_sa[o] = red_sa[0][tid] + red_sa[1][tid];
    ws_sp[o] = red_sp[0][tid] + red_sp[1][tid];
    ws_mx[o] = fmaxf(red_mx[0][tid], red_mx[1][tid]);
  }
}

// -------- Kernel 3: combine chunk partials -> per-row loss -> 32 block partials --------
__global__ void finalize_rows_kernel(const float* __restrict__ ws_sp,
                                     const float* __restrict__ ws_sa,
                                     const float* __restrict__ ws_mx,
                                     float* __restrict__ ws_part) {
  int r = blockIdx.x * blockDim.x + threadIdx.x;
  float sp = 0.f, sa = 0.f, mx = NEGINF;
  #pragma unroll 8
  for (int c = 0; c < NCHUNK; ++c) {
    sp += ws_sp[(size_t)c * N_ROWS + r];
    sa += ws_sa[(size_t)c * N_ROWS + r];
    mx = fmaxf(mx, ws_mx[(size_t)c * N_ROWS + r]);
  }
  float frac = (sp + 1e-8f) / (sa + 1e-8f);
  frac = fminf(fmaxf(frac, 1e-8f), 1.0f);
  float loss = -logf(frac);
  if (sp == 0.0f) loss = -mx;   // no-positives fallback (every exp term > 0)
  // deterministic in-block reduction
  int t = threadIdx.x;
  #pragma unroll
  for (int m = 1; m < 64; m <<= 1) loss += __shfl_xor(loss, m);
  __shared__ float wsum[4];
  if ((t & 63) == 0) wsum[t >> 6] = loss;
  __syncthreads();
  if (t == 0) ws_part[blockIdx.x] = (wsum[0] + wsum[1]) + (wsum[2] + wsum[3]);
}

// -------- Kernel 4: deterministic mean over 32 block partials --------
__global__ void mean_kernel(const float* __restrict__ ws_part, float* __restrict__ out) {
  int t = threadIdx.x;                       // 64 threads
  float s = (t < N_ROWS / 256) ? ws_part[t] : 0.f;
  #pragma unroll
  for (int m = 1; m < 64; m <<= 1) s += __shfl_xor(s, m);
  if (t == 0) out[0] = s * (1.0f / N_ROWS);
}

extern "C" void kernel_launch(void* const* d_in, const int* in_sizes, int n_in,
                              void* d_out, int out_size, void* d_ws, size_t ws_size,
                              hipStream_t stream) {
  const float* ctx = (const float*)d_in[0];
  const float* gls = (const float*)d_in[1];
  const int* labels = (const int*)d_in[2];
  float* out = (float*)d_out;

  char* ws = (char*)d_ws;
  unsigned char* Cn = (unsigned char*)ws;                                 // 8 MiB
  unsigned char* Gn = (unsigned char*)(ws + (size_t)N_ROWS * DIM);        // 8 MiB
  float* CnS = (float*)(ws + (size_t)2 * N_ROWS * DIM);                   // 32 KiB
  float* GnS = CnS + N_ROWS;                                              // 32 KiB
  float* ws_sp = GnS + N_ROWS;
  float* ws_sa = ws_sp + (size_t)NCHUNK * N_ROWS;
  float* ws_mx = ws_sa + (size_t)NCHUNK * N_ROWS;
  float* ws_part = ws_mx + (size_t)NCHUNK * N_ROWS;

  hipLaunchKernelGGL(norm_i8_kernel, dim3(4096), dim3(256), 0, stream,
                     ctx, gls, Cn, Gn, CnS, GnS);
  hipLaunchKernelGGL(gemm_reduce_kernel, dim3(N_ROWS / BM, NCHUNK), dim3(256), 0, stream,
                     Cn, Gn, CnS, GnS, labels, ws_sp, ws_sa, ws_mx);
  hipLaunchKernelGGL(finalize_rows_kernel, dim3(N_ROWS / 256), dim3(256), 0, stream,
                     ws_sp, ws_sa, ws_mx, ws_part);
  hipLaunchKernelGGL(mean_kernel, dim3(1), dim3(64), 0, stream, ws_part, out);
}